// Round 4
// baseline (422.736 us; speedup 1.0000x reference)
//
#include <hip/hip_runtime.h>
#include <cstdint>
#include <cmath>

#define N_HEADS 16
#define I_DIM 128
#define H_DIM 128
#define B_SZ 16
#define T_SZ 512
#define G3 384           // 3*H
#define BT (B_SZ * T_SZ) // 8192
#define LDW 136          // padded LDS row stride in bf16 (128+8), keeps 16B align
#define OUT_HN_OFFSET ((size_t)B_SZ * T_SZ * (N_HEADS * H_DIM)) // 16777216
#define CHUNK 8
#define NCHUNK (T_SZ / CHUNK) // 64

typedef __attribute__((ext_vector_type(8))) short bf16x8;
typedef __attribute__((ext_vector_type(4))) float f32x4;

static __device__ __forceinline__ unsigned short f2bf(float f) {
  unsigned int u = __float_as_uint(f);
  unsigned int r = (u + 0x7FFFu + ((u >> 16) & 1u)) >> 16; // RNE
  return (unsigned short)r;
}
static __device__ __forceinline__ float bf2f(unsigned short s) {
  return __uint_as_float((unsigned int)s << 16);
}
static __device__ __forceinline__ uint2 pack4(float4 v) {
  uint2 p;
  p.x = (unsigned int)f2bf(v.x) | ((unsigned int)f2bf(v.y) << 16);
  p.y = (unsigned int)f2bf(v.z) | ((unsigned int)f2bf(v.w) << 16);
  return p;
}
static __device__ __forceinline__ bf16x8 pack8(float4 a, float4 b) {
  union { uint2 u[2]; bf16x8 v; } r;
  r.u[0] = pack4(a);
  r.u[1] = pack4(b);
  return r.v;
}

// ---------------------------------------------------------------------------
// Kernel A v3: bf16 MFMA GEMM for gates_x. Gates layout is now TRANSPOSED to
// [N][G3][BT] so that each lane's 4 accumulator rows (consecutive bt, same g)
// form ONE packed uint2 (4xbf16) store. R3 arithmetic showed A's ~125us was
// store-transaction-bound: 768 scattered 2B stores/thread. Now 192 8B stores
// per thread, and within one store instr the 4 quads of a wave complete full
// 64B lines for 16 g-rows (perfectly line-coalesced).
// MFMA/fragment/bias math identical to R3 (bitwise same values).
// ---------------------------------------------------------------------------
__global__ __launch_bounds__(256) void gates_x_mfma(
    const float* __restrict__ x, const float* __restrict__ w_ih,
    const float* __restrict__ b_ih, unsigned short* __restrict__ gates) {
  const int n = blockIdx.z;
  const int grp = blockIdx.x; // 0..15, 8 tiles of 64 bt-rows each
  const int tid = threadIdx.x;
  const int wave = tid >> 6;
  const int lane = tid & 63;
  const int m16 = lane & 15;
  const int quad = lane >> 4;

  extern __shared__ __align__(16) unsigned short lds_pool[];
  unsigned short* Ws = lds_pool;            // G3*LDW ushorts = 104,448 B
  unsigned short* Xs = lds_pool + G3 * LDW; // 64*LDW ushorts =  17,408 B

  const int xrow = tid >> 2;
  const int xq = tid & 3;

  float4 xf[8];
  {
    const float4* xg =
        (const float4*)(x + (size_t)(grp * 512 + xrow) * 2048 + n * I_DIM) +
        xq * 8;
#pragma unroll
    for (int i = 0; i < 8; ++i) xf[i] = xg[i];
  }

  {
    const float4* wsrc = (const float4*)(w_ih + (size_t)n * G3 * I_DIM);
#pragma unroll
    for (int i = 0; i < 48; ++i) {
      const int idx = i * 256 + tid; // f4 index
      *(uint2*)&Ws[(idx >> 5) * LDW + (idx & 31) * 4] = pack4(wsrc[idx]);
    }
  }

  float bias[3][8];
#pragma unroll
  for (int gb = 0; gb < 3; ++gb)
#pragma unroll
    for (int j = 0; j < 8; ++j)
      bias[gb][j] = b_ih[n * G3 + gb * 128 + j * 16 + m16];

  for (int tile = 0; tile < 8; ++tile) {
    const int bt0 = grp * 512 + tile * 64;

    __syncthreads();
#pragma unroll
    for (int i = 0; i < 8; ++i)
      *(uint2*)&Xs[xrow * LDW + xq * 32 + i * 4] = pack4(xf[i]);
    __syncthreads();

    if (tile < 7) {
      const float4* xg =
          (const float4*)(x + (size_t)(bt0 + 64 + xrow) * 2048 + n * I_DIM) +
          xq * 8;
#pragma unroll
      for (int i = 0; i < 8; ++i) xf[i] = xg[i];
    }

#pragma unroll
    for (int gb = 0; gb < 3; ++gb) {
      f32x4 acc[8];
#pragma unroll
      for (int j = 0; j < 8; ++j) acc[j] = (f32x4){0.f, 0.f, 0.f, 0.f};

#pragma unroll
      for (int kt = 0; kt < 4; ++kt) {
        const bf16x8 afrag =
            *(const bf16x8*)&Xs[(wave * 16 + m16) * LDW + kt * 32 + quad * 8];
#pragma unroll
        for (int j = 0; j < 8; ++j) {
          const bf16x8 bfrag =
              *(const bf16x8*)&Ws[(gb * 128 + j * 16 + m16) * LDW + kt * 32 +
                                  quad * 8];
          acc[j] = __builtin_amdgcn_mfma_f32_16x16x32_bf16(afrag, bfrag,
                                                           acc[j], 0, 0, 0);
        }
      }

      // Epilogue: bias + packed bf16 store. Lane's 4 rows = bt quad*4+0..3,
      // same g -> one uint2 at gates[(n*G3+g)*BT + bt].
#pragma unroll
      for (int j = 0; j < 8; ++j) {
        const int g = gb * 128 + j * 16 + m16;
        float4 v;
        v.x = acc[j][0] + bias[gb][j];
        v.y = acc[j][1] + bias[gb][j];
        v.z = acc[j][2] + bias[gb][j];
        v.w = acc[j][3] + bias[gb][j];
        const int bt = bt0 + wave * 16 + quad * 4;
        *(uint2*)&gates[((size_t)n * G3 + g) * BT + bt] = pack4(v);
      }
    }
  }
}

// ---------------------------------------------------------------------------
// Kernel B v5: MFMA scan, DS/VALU-trimmed. One WG (256 thr = 4 waves) per
// (b,n). Structure as v4 (one barrier/step, h dbuf, chunked gates, batched
// out stores). R3 counters: MFMA pipe 400cy/step (single-wave issue rate),
// VALU ~550cy, DS/waits ~440cy. This round trims DS+VALU:
//  * gates chunk-staged into [s][e][{r,z,n,pad}] ushort layout (scatter once
//    per 8 steps, amortized) -> per-step gx is ONE ds_read_b64 per upd lane
//    (was 3 ds_read_u16), unpacked with 3 shifts (no bf2f chain).
//  * all 4 h A-fragments hoisted into regs before the MFMA block.
//  * tanh via 2*sigmoid(2x)-1 (kills the fabs/cndmask/rcp-tail chain;
//    correct limits at +-inf).
// ---------------------------------------------------------------------------
__global__ __launch_bounds__(256, 1) void gru_scan_kernel(
    const float* __restrict__ h0, const float* __restrict__ w_hh,
    const float* __restrict__ b_hh, const unsigned short* __restrict__ gates,
    float* __restrict__ out) {
  const int b = blockIdx.x >> 4;
  const int n = blockIdx.x & 15;
  const int tid = threadIdx.x;
  const int wave = tid >> 6;
  const int lane = tid & 63;
  const int m16 = lane & 15;
  const int quad = lane >> 4;

  __shared__ __align__(16) unsigned short h2[2][2][H_DIM];     // [buf][hi|lo]
  __shared__ __align__(16) unsigned short gbuf[2][CHUNK * 512]; // [s][e][4]

  // Register-resident W_hh bf16 B-fragments (verified layout).
  // j -> colblock: {2w, 8+2w, 16+2w, 2w+1, 9+2w, 17+2w}  (r0,z0,n0,r1,z1,n1)
  bf16x8 wf[6][4];
  {
    const int cb0 = 2 * wave;
    const int cbs[6] = {cb0, 8 + cb0, 16 + cb0, cb0 + 1, 9 + cb0, 17 + cb0};
#pragma unroll
    for (int j = 0; j < 6; ++j) {
      const int g = cbs[j] * 16 + m16;
      const float4* wr = (const float4*)(w_hh + ((size_t)n * G3 + g) * H_DIM);
#pragma unroll
      for (int kt = 0; kt < 4; ++kt)
        wf[j][kt] = pack8(wr[kt * 8 + quad * 2], wr[kt * 8 + quad * 2 + 1]);
    }
  }

  const bool upd = quad < 2;                    // updating lanes (128 total)
  const int elem = wave * 32 + quad * 16 + m16; // h element owned (if upd)

  float bh_r = 0.f, bh_z = 0.f, bh_n = 0.f, h_old = 0.f;
  if (upd) {
    bh_r = b_hh[n * G3 + elem];
    bh_z = b_hh[n * G3 + elem + 128];
    bh_n = b_hh[n * G3 + elem + 256];
    h_old = h0[(size_t)b * 2048 + n * H_DIM + elem];
    const unsigned short hh = f2bf(h_old);
    h2[0][0][elem] = hh;
    h2[0][1][elem] = f2bf(h_old - bf2f(hh));
  }

  // Gates rows this WG reads: row g at [(n*G3+g)*BT + b*512 + t] (ushorts).
  // Thread handles row g0 = tid and (if tid<128) g1 = 256+tid.
  const size_t grow0 = ((size_t)n * G3 + tid) * BT + (size_t)b * T_SZ;
  const size_t grow1 = ((size_t)n * G3 + 256 + tid) * BT + (size_t)b * T_SZ;

  // Scatter one row's 8-step uint4 into gbuf layout [s][e][gb3].
  auto scatter = [&](unsigned short* buf, int g, uint4 v) {
    unsigned short* d = buf + (g & 127) * 4 + (g >> 7);
    d[0]    = (unsigned short)v.x;
    d[512]  = (unsigned short)(v.x >> 16);
    d[1024] = (unsigned short)v.y;
    d[1536] = (unsigned short)(v.y >> 16);
    d[2048] = (unsigned short)v.z;
    d[2560] = (unsigned short)(v.z >> 16);
    d[3072] = (unsigned short)v.w;
    d[3584] = (unsigned short)(v.w >> 16);
  };

  // Prologue: stage chunk 0.
  uint4 pfA, pfB;
  pfA = *(const uint4*)(gates + grow0);
  if (tid < 128) pfB = *(const uint4*)(gates + grow1);
  scatter(gbuf[0], tid, pfA);
  if (tid < 128) scatter(gbuf[0], 256 + tid, pfB);
  __syncthreads();

  float* out_base = out + (size_t)b * T_SZ * 2048 + n * H_DIM;
  float oreg[CHUNK];

  for (int c = 0; c < NCHUNK; ++c) {
    const int gb = c & 1;

    // Issue next chunk's global loads (16B per row); retire over ~8 steps.
    if (c + 1 < NCHUNK) {
      pfA = *(const uint4*)(gates + grow0 + (size_t)(c + 1) * CHUNK);
      if (tid < 128)
        pfB = *(const uint4*)(gates + grow1 + (size_t)(c + 1) * CHUNK);
    }

#pragma unroll
    for (int s = 0; s < CHUNK; ++s) {
      const int rb = s & 1; // chunk length even -> parity restarts at 0
      const int wb = rb ^ 1;

      // gates_x: ONE b64 read -> {r, z, n, pad} bf16; unpack = 3 shifts.
      uint2 gxu = {0u, 0u};
      if (upd) gxu = *(const uint2*)&gbuf[gb][s * 512 + elem * 4];
      const float gxr = __uint_as_float(gxu.x << 16);
      const float gxz = __uint_as_float(gxu.x & 0xffff0000u);
      const float gxn = __uint_as_float(gxu.y << 16);

      // Hoisted h A-fragments (hi for even m16, lo for odd).
      const unsigned short* hsrc = &h2[rb][m16 & 1][0];
      const bf16x8 av0 = *(const bf16x8*)&hsrc[0 * 32 + quad * 8];
      const bf16x8 av1 = *(const bf16x8*)&hsrc[1 * 32 + quad * 8];
      const bf16x8 av2 = *(const bf16x8*)&hsrc[2 * 32 + quad * 8];
      const bf16x8 av3 = *(const bf16x8*)&hsrc[3 * 32 + quad * 8];

      f32x4 acc[6];
#pragma unroll
      for (int j = 0; j < 6; ++j) acc[j] = (f32x4){0.f, 0.f, 0.f, 0.f};
#pragma unroll
      for (int j = 0; j < 6; ++j)
        acc[j] = __builtin_amdgcn_mfma_f32_16x16x32_bf16(av0, wf[j][0],
                                                         acc[j], 0, 0, 0);
#pragma unroll
      for (int j = 0; j < 6; ++j)
        acc[j] = __builtin_amdgcn_mfma_f32_16x16x32_bf16(av1, wf[j][1],
                                                         acc[j], 0, 0, 0);
#pragma unroll
      for (int j = 0; j < 6; ++j)
        acc[j] = __builtin_amdgcn_mfma_f32_16x16x32_bf16(av2, wf[j][2],
                                                         acc[j], 0, 0, 0);
#pragma unroll
      for (int j = 0; j < 6; ++j)
        acc[j] = __builtin_amdgcn_mfma_f32_16x16x32_bf16(av3, wf[j][3],
                                                         acc[j], 0, 0, 0);

      if (upd) {
        // D[4q] = W.h_hi, D[4q+1] = W.h_lo (valid in every quad).
        const float ghr =
            (quad ? acc[3][0] + acc[3][1] : acc[0][0] + acc[0][1]) + bh_r;
        const float ghz =
            (quad ? acc[4][0] + acc[4][1] : acc[1][0] + acc[1][1]) + bh_z;
        const float ghn =
            (quad ? acc[5][0] + acc[5][1] : acc[2][0] + acc[2][1]) + bh_n;
        const float r = 1.f / (1.f + __expf(-(gxr + ghr)));
        const float z = 1.f / (1.f + __expf(-(gxz + ghz)));
        const float targ = gxn + r * ghn;
        const float rt = 1.f / (1.f + __expf(-2.f * targ)); // sigmoid(2x)
        const float nn = 2.f * rt - 1.f;                    // tanh(targ)
        const float hn = (1.f - z) * nn + z * h_old;
        const unsigned short hh = f2bf(hn);
        h2[wb][0][elem] = hh;
        h2[wb][1][elem] = f2bf(hn - bf2f(hh));
        h_old = hn;
        oreg[s] = hn;
      }

      // Stage next chunk into the other gbuf before the last step-barrier.
      if (s == CHUNK - 1 && c + 1 < NCHUNK) {
        scatter(gbuf[gb ^ 1], tid, pfA);
        if (tid < 128) scatter(gbuf[gb ^ 1], 256 + tid, pfB);
      }
      __syncthreads();
    }

    // Batched out stores (retire under next chunk).
    if (upd) {
#pragma unroll
      for (int s = 0; s < CHUNK; ++s)
        out_base[(size_t)(c * CHUNK + s) * 2048 + elem] = oreg[s];
    }
  }

  if (upd) {
    out[OUT_HN_OFFSET + (size_t)b * 2048 + n * H_DIM + elem] = h_old;
  }
}

extern "C" void kernel_launch(void* const* d_in, const int* in_sizes, int n_in,
                              void* d_out, int out_size, void* d_ws,
                              size_t ws_size, hipStream_t stream) {
  const float* x    = (const float*)d_in[0]; // [B, T, N*I]
  const float* h0   = (const float*)d_in[1]; // [1, B, N*H]
  const float* w_ih = (const float*)d_in[2]; // [N, 3H, I]
  const float* w_hh = (const float*)d_in[3]; // [N, 3H, H]
  const float* b_ih = (const float*)d_in[4]; // [N, 3H]
  const float* b_hh = (const float*)d_in[5]; // [N, 3H]
  float* out = (float*)d_out;
  unsigned short* gates = (unsigned short*)d_ws; // [N][G3][BT] bf16 = 96 MB

  // Kernel A uses 122 KB LDS (full W_ih[n] resident): opt in past 64 KB.
  static bool lds_opt_in = false;
  if (!lds_opt_in) {
    (void)hipFuncSetAttribute(reinterpret_cast<const void*>(&gates_x_mfma),
                              hipFuncAttributeMaxDynamicSharedMemorySize,
                              (G3 + 64) * LDW * (int)sizeof(unsigned short));
    lds_opt_in = true;
  }

  dim3 gridA(16, 1, N_HEADS);
  gates_x_mfma<<<gridA, 256, (G3 + 64) * LDW * sizeof(unsigned short),
                 stream>>>(x, w_ih, b_ih, gates);
  gru_scan_kernel<<<256, 256, 0, stream>>>(h0, w_hh, b_hh, gates, out);
}